// Round 4
// baseline (153.331 us; speedup 1.0000x reference)
//
#include <hip/hip_runtime.h>

// FlexAttention (sliding-window causal + per-head sink), R4.
// B=2,H=16,S=2048,D=64,W=1024.
//
// Equal-work blocks: per bh, 16 solo items (qt=16..31, 17 tiles) + 8 pair
// items ((p,15-p), (p+1)+(16-p)=17 tiles) -> grid = B*H*24 = 768 blocks,
// each EXACTLY 17 staged K-tiles. 3 blocks/CU, all co-resident -> flat
// 12 waves/CU (was: imbalanced 8 decaying, OccupancyPercent 13%).
//
// Block = 256 threads = 4 waves; wave w owns q-rows [q0+16w, q0+16w+16)
// via 16x16x32 bf16 MFMA. Per 64-key tile:
//   S^T = K·Q^T (4 key-tiles x 2 k-steps = 8 mfma); C: col=q(l&15),
//   row=key(quad*4+reg) -> softmax per-lane over 16 regs + shfl_xor(16,32).
//   P -> per-wave LDS [q][key] (b64 writes, b128 reads, no barrier).
//   O^T = V^T·P^T (8 mfma). Epilogue: O^T -> LDS transpose -> float4 stores.
// Layouts (m89/m91/m120): A[m=l&15][k=(l>>4)*8+j], B[k=(l>>4)*8+j][n=l&15],
// C/D[row=(l>>4)*4+reg][col=l&15].

typedef __bf16 bf16x8 __attribute__((ext_vector_type(8)));
typedef __bf16 bf16x4 __attribute__((ext_vector_type(4)));
typedef float  f32x4  __attribute__((ext_vector_type(4)));

#define SK 72      // bf16 elems per LDS row (144 B)
#define SV 72
#define SPP 72
#define SO 68      // f32 elems per epilogue row (272 B, 16B-aligned)
#define NT 256

__global__ __launch_bounds__(NT, 3) void flex_attn_r4(
    const float* __restrict__ Q, const float* __restrict__ K,
    const float* __restrict__ V, const float* __restrict__ SINKW,
    const int* __restrict__ SWIN, float* __restrict__ OUT,
    const int H, const int S, const int NBH)
{
    const int t    = threadIdx.x;
    const int lane = t & 63;
    const int w    = t >> 6;        // wave id: q-rows [q0+16w, q0+16w+16)
    const int r    = lane & 15;
    const int quad = lane >> 4;
    const int W    = SWIN[0];
    const float scale = 0.125f;     // 1/sqrt(64)

    __shared__ __align__(16) unsigned char smem[27648];
    __bf16* k_lds = (__bf16*)smem;            // K   [key][dim], 64xSK
    __bf16* v_lds = (__bf16*)(smem + 9216);   // V^T [dim][key], 64xSV
    __bf16* p_lds = (__bf16*)(smem + 18432);  // P   [4 waves][16 q][SPP]
    float*  o_lds = (float*)smem;             // epilogue [4 waves][16 q][SO]

    // ---- equal-cost work-item mapping ----
    const int id = blockIdx.x;
    int bh, qtA, qtB, nphase;
    if (id < NBH * 16) {            // solo heavy: 17 tiles
        bh = id >> 4; qtA = 16 + (id & 15); qtB = 0; nphase = 1;
    } else {                        // pair: (p+1) + (16-p) = 17 tiles
        const int j = id - NBH * 16;
        bh = j >> 3; const int p = j & 7;
        qtA = p; qtB = 15 - p; nphase = 2;
    }

    const size_t basebh = (size_t)bh * S * 64;
    const int h = bh % H;
    const float sw = SINKW[h];
    const float4* kp4 = (const float4*)(K + basebh);
    const float4* vp4 = (const float4*)(V + basebh);
    const int dgi = t & 15;         // V staging: dims 4dgi..4dgi+3
    const int kgi = t >> 4;         // V staging: keys 4kgi..4kgi+3

    float4 kreg[4], vreg[4];

    for (int ph = 0; ph < nphase; ++ph) {
        const int qt  = ph ? qtB : qtA;
        const int q0  = qt * 64;
        const int qw0 = q0 + 16 * w;
        const int qi  = qw0 + r;

        // ---- Q B-fragments (pre-scaled) ----
        bf16x8 bq[2];
        {
            const float4* qp4 = (const float4*)(Q + basebh + (size_t)qi * 64);
            #pragma unroll
            for (int ks = 0; ks < 2; ++ks) {
                float4 f0 = qp4[8 * ks + 2 * quad];
                float4 f1 = qp4[8 * ks + 2 * quad + 1];
                bq[ks][0] = (__bf16)(f0.x * scale); bq[ks][1] = (__bf16)(f0.y * scale);
                bq[ks][2] = (__bf16)(f0.z * scale); bq[ks][3] = (__bf16)(f0.w * scale);
                bq[ks][4] = (__bf16)(f1.x * scale); bq[ks][5] = (__bf16)(f1.y * scale);
                bq[ks][6] = (__bf16)(f1.z * scale); bq[ks][7] = (__bf16)(f1.w * scale);
            }
        }

        float mrun = sw, lrun = 1.0f;
        f32x4 accO[4];
        #pragma unroll
        for (int i = 0; i < 4; ++i) { accO[i].x = 0.f; accO[i].y = 0.f; accO[i].z = 0.f; accO[i].w = 0.f; }

        int lo = q0 - W; if (lo < 0) lo = 0;
        const int kt0 = lo >> 6, kt1 = qt;

        // prefetch first tile
        #pragma unroll
        for (int i = 0; i < 4; ++i) kreg[i] = kp4[kt0 * 1024 + i * NT + t];
        #pragma unroll
        for (int kk = 0; kk < 4; ++kk) vreg[kk] = vp4[kt0 * 1024 + (4 * kgi + kk) * 16 + dgi];

        for (int kt = kt0; kt <= kt1; ++kt) {
            const int k0 = kt * 64;
            __syncthreads();   // B1: prev tile's LDS reads (and epilogue reads) done

            // ---- stage K [key][dim] ----
            #pragma unroll
            for (int i = 0; i < 4; ++i) {
                const int flat = i * NT + t;
                const int key = flat >> 4, dd = flat & 15;
                float4 f = kreg[i];
                bf16x4 b = { (__bf16)f.x, (__bf16)f.y, (__bf16)f.z, (__bf16)f.w };
                *(bf16x4*)&k_lds[key * SK + 4 * dd] = b;
            }
            // ---- stage V^T [dim][key] (register transpose of 4x4 block) ----
            {
                float4 a0 = vreg[0], a1 = vreg[1], a2 = vreg[2], a3 = vreg[3];
                bf16x4 w0 = { (__bf16)a0.x, (__bf16)a1.x, (__bf16)a2.x, (__bf16)a3.x };
                bf16x4 w1 = { (__bf16)a0.y, (__bf16)a1.y, (__bf16)a2.y, (__bf16)a3.y };
                bf16x4 w2 = { (__bf16)a0.z, (__bf16)a1.z, (__bf16)a2.z, (__bf16)a3.z };
                bf16x4 w3 = { (__bf16)a0.w, (__bf16)a1.w, (__bf16)a2.w, (__bf16)a3.w };
                *(bf16x4*)&v_lds[(4 * dgi + 0) * SV + 4 * kgi] = w0;
                *(bf16x4*)&v_lds[(4 * dgi + 1) * SV + 4 * kgi] = w1;
                *(bf16x4*)&v_lds[(4 * dgi + 2) * SV + 4 * kgi] = w2;
                *(bf16x4*)&v_lds[(4 * dgi + 3) * SV + 4 * kgi] = w3;
            }
            // prefetch next tile (hidden behind compute)
            if (kt < kt1) {
                #pragma unroll
                for (int i = 0; i < 4; ++i) kreg[i] = kp4[(kt + 1) * 1024 + i * NT + t];
                #pragma unroll
                for (int kk = 0; kk < 4; ++kk) vreg[kk] = vp4[(kt + 1) * 1024 + (4 * kgi + kk) * 16 + dgi];
            }
            __syncthreads();   // B2: tiles visible

            // ---- S^T = K · Q^T ----
            f32x4 accS[4];
            #pragma unroll
            for (int n = 0; n < 4; ++n) { accS[n].x = 0.f; accS[n].y = 0.f; accS[n].z = 0.f; accS[n].w = 0.f; }
            #pragma unroll
            for (int ks = 0; ks < 2; ++ks)
                #pragma unroll
                for (int n = 0; n < 4; ++n) {
                    bf16x8 ka = *(const bf16x8*)&k_lds[(n * 16 + r) * SK + ks * 32 + quad * 8];
                    accS[n] = __builtin_amdgcn_mfma_f32_16x16x32_bf16(ka, bq[ks], accS[n], 0, 0, 0);
                }

            // ---- mask (wave-uniform skip for interior tiles) ----
            const bool interior = (k0 + 63 <= qw0) && (qw0 + 15 - k0 <= W);
            if (!interior) {
                #pragma unroll
                for (int n = 0; n < 4; ++n)
                    #pragma unroll
                    for (int reg = 0; reg < 4; ++reg) {
                        const int key = k0 + n * 16 + 4 * quad + reg;
                        if (!((key <= qi) && (qi - key <= W))) accS[n][reg] = -1e30f;
                    }
            }

            // ---- online softmax (16 keys/lane + cross-quad shfl) ----
            float mx = fmaxf(fmaxf(accS[0][0], accS[0][1]), fmaxf(accS[0][2], accS[0][3]));
            #pragma unroll
            for (int n = 1; n < 4; ++n)
                mx = fmaxf(mx, fmaxf(fmaxf(accS[n][0], accS[n][1]), fmaxf(accS[n][2], accS[n][3])));
            mx = fmaxf(mx, __shfl_xor(mx, 16, 64));
            mx = fmaxf(mx, __shfl_xor(mx, 32, 64));
            const float mnew  = fmaxf(mrun, mx);
            const float alpha = __expf(mrun - mnew);
            float ps = 0.0f;
            #pragma unroll
            for (int n = 0; n < 4; ++n)
                #pragma unroll
                for (int reg = 0; reg < 4; ++reg) {
                    const float p = __expf(accS[n][reg] - mnew);
                    accS[n][reg] = p;
                    ps += p;
                }
            ps += __shfl_xor(ps, 16, 64);
            ps += __shfl_xor(ps, 32, 64);
            lrun = lrun * alpha + ps;
            mrun = mnew;
            #pragma unroll
            for (int n = 0; n < 4; ++n) {
                accO[n].x *= alpha; accO[n].y *= alpha; accO[n].z *= alpha; accO[n].w *= alpha;
            }

            // ---- P -> per-wave LDS [q][key] (no barrier: intra-wave) ----
            __bf16* pw = p_lds + w * 16 * SPP;
            #pragma unroll
            for (int n = 0; n < 4; ++n) {
                bf16x4 b = { (__bf16)accS[n][0], (__bf16)accS[n][1],
                             (__bf16)accS[n][2], (__bf16)accS[n][3] };
                *(bf16x4*)&pw[r * SPP + n * 16 + 4 * quad] = b;
            }

            // ---- O^T += V^T · P^T ----
            #pragma unroll
            for (int ks = 0; ks < 2; ++ks) {
                bf16x8 bp = *(const bf16x8*)&pw[r * SPP + ks * 32 + quad * 8];
                #pragma unroll
                for (int dt = 0; dt < 4; ++dt) {
                    bf16x8 va = *(const bf16x8*)&v_lds[(dt * 16 + r) * SV + ks * 32 + quad * 8];
                    accO[dt] = __builtin_amdgcn_mfma_f32_16x16x32_bf16(va, bp, accO[dt], 0, 0, 0);
                }
            }
        }

        // ---- epilogue: O^T -> LDS transpose -> coalesced float4 stores ----
        __syncthreads();   // all waves done with k/v/p before o_lds overwrites
        float* ow = o_lds + w * 16 * SO;
        const float inv = 1.0f / lrun;
        #pragma unroll
        for (int dt = 0; dt < 4; ++dt)
            #pragma unroll
            for (int reg = 0; reg < 4; ++reg)
                ow[r * SO + dt * 16 + 4 * quad + reg] = accO[dt][reg] * inv;
        // intra-wave read-back (compiler inserts lgkmcnt)
        const int q2 = lane >> 2, j4 = lane & 3;
        float* dst = OUT + basebh + (size_t)(qw0 + q2) * 64;
        #pragma unroll
        for (int c2 = 0; c2 < 4; ++c2) {
            float4 vv = *(const float4*)&ow[q2 * SO + c2 * 16 + j4 * 4];
            *(float4*)&dst[c2 * 16 + j4 * 4] = vv;
        }
    }
}

extern "C" void kernel_launch(void* const* d_in, const int* in_sizes, int n_in,
                              void* d_out, int out_size, void* d_ws, size_t ws_size,
                              hipStream_t stream) {
    const float* q     = (const float*)d_in[0];
    const float* k     = (const float*)d_in[1];
    const float* v     = (const float*)d_in[2];
    const float* sinkw = (const float*)d_in[3];
    const int*   swin  = (const int*)d_in[4];
    float* out = (float*)d_out;

    const int H = in_sizes[3];                   // 16
    const int S = 2048;
    const int B = in_sizes[0] / (H * S * 64);    // 2
    const int NBH = B * H;                       // 32

    dim3 grid(NBH * 24);                         // 768 equal-cost blocks
    flex_attn_r4<<<grid, NT, 0, stream>>>(q, k, v, sinkw, swin, out, H, S, NBH);
}

// Round 5
// 139.916 us; speedup vs baseline: 1.0959x; 1.0959x over previous
//
#include <hip/hip_runtime.h>

// FlexAttention (sliding-window causal + per-head sink), R5.
// B=2,H=16,S=2048,D=64,W=1024.
//
// 128-q work items (16 per bh). Item qt' needs T = 2qt'+2 (qt'<=7) or 18
// (qt'>=8) K-tiles; per-bh total = 216 = 24 x 9. Baked schedule: 24 blocks/bh,
// each EXACTLY 9 staged tiles, items split at K-boundaries (<=3 segs/item,
// <=3 segs/block). Grid = 768 equal blocks = 3/CU -> flat 12 waves/CU.
// Block = 256 thr = 4 waves x 32-q (32x32x16 MFMA, R3's per-q efficiency);
// K/V staged once per block serve 128 q-rows (staging per-q halved vs R3/R4).
// Every segment writes partials (m,l fp32; O bf16 unnormalized) to d_ws;
// combine kernel merges <=3 segs/item (sink credited to seg 0 only).
// Layouts (m74/m101): A[m=l&31][k=(l>>5)*8+j], B[k=..][n=l&31],
// C/D[row=(rg&3)+8*(rg>>2)+4*(l>>5)][col=l&31].

typedef __bf16 bf16x8 __attribute__((ext_vector_type(8)));
typedef __bf16 bf16x4 __attribute__((ext_vector_type(4)));
typedef float  f32x16 __attribute__((ext_vector_type(16)));

#define SK 72
#define SV 72
#define SPP 72
#define NT 256
#define NEG_BIG (-3.0e38f)

// ---- baked schedule: per (blockIdx.x % 24): segments {item, j0, j1, sidx} ----
// light items 0..7 (T=2,4,6,8,10,12,14,16) chunked into 9s with straddling;
// heavy items 8..15 (T=18) split 9+9.
__device__ const int SEG_N[24] = {3,2,2,2,2,1,2,1, 1,1,1,1,1,1,1,1, 1,1,1,1,1,1,1,1};
__device__ const int SEG_IT[24][3] = {
  {0,1,2},{2,3,0},{3,4,0},{4,5,0},{5,6,0},{6,0,0},{6,7,0},{7,0,0},
  {8,0,0},{8,0,0},{9,0,0},{9,0,0},{10,0,0},{10,0,0},{11,0,0},{11,0,0},
  {12,0,0},{12,0,0},{13,0,0},{13,0,0},{14,0,0},{14,0,0},{15,0,0},{15,0,0}};
__device__ const int SEG_J0[24][3] = {
  {0,0,0},{3,0,0},{6,0,0},{7,0,0},{6,0,0},{3,0,0},{12,0,0},{7,0,0},
  {0,0,0},{9,0,0},{0,0,0},{9,0,0},{0,0,0},{9,0,0},{0,0,0},{9,0,0},
  {0,0,0},{9,0,0},{0,0,0},{9,0,0},{0,0,0},{9,0,0},{0,0,0},{9,0,0}};
__device__ const int SEG_J1[24][3] = {
  {2,4,3},{6,6,0},{8,7,0},{10,6,0},{12,3,0},{12,0,0},{14,7,0},{16,0,0},
  {9,0,0},{18,0,0},{9,0,0},{18,0,0},{9,0,0},{18,0,0},{9,0,0},{18,0,0},
  {9,0,0},{18,0,0},{9,0,0},{18,0,0},{9,0,0},{18,0,0},{9,0,0},{18,0,0}};
__device__ const int SEG_SX[24][3] = {
  {0,0,0},{1,0,0},{1,0,0},{1,0,0},{1,0,0},{1,0,0},{2,0,0},{1,0,0},
  {0,0,0},{1,0,0},{0,0,0},{1,0,0},{0,0,0},{1,0,0},{0,0,0},{1,0,0},
  {0,0,0},{1,0,0},{0,0,0},{1,0,0},{0,0,0},{1,0,0},{0,0,0},{1,0,0}};
// segments per item (combine)
__device__ const int NSEG_ITEM[16] = {1,1,2,2,2,2,3,2, 2,2,2,2,2,2,2,2};

__global__ __launch_bounds__(NT, 3) void flex_r5_main(
    const float* __restrict__ Q, const float* __restrict__ K,
    const float* __restrict__ V, const float* __restrict__ SINKW,
    const int* __restrict__ SWIN, void* __restrict__ WS,
    const int H, const int S)
{
    const int t    = threadIdx.x;
    const int lane = t & 63;
    const int w    = t >> 6;        // wave id: q-rows [item*128+32w, +32)
    const int c    = lane & 31;
    const int hl   = lane >> 5;
    const int W    = SWIN[0];
    const float scale = 0.125f;

    const int NBH = gridDim.x / 24;
    const int bh  = blockIdx.x / 24;
    const int b24 = blockIdx.x - bh * 24;
    const int h   = bh % H;
    const float sw = SINKW[h];

    __shared__ __align__(16) __bf16 k_lds[64 * SK];   // K   [key][dim]
    __shared__ __align__(16) __bf16 v_lds[64 * SV];   // V^T [dim][key]
    __shared__ __align__(16) __bf16 p_lds[4 * 32 * SPP];

    const size_t basebh = (size_t)bh * S * 64;
    const float4* kp4 = (const float4*)(K + basebh);
    const float4* vp4 = (const float4*)(V + basebh);
    __bf16* O_ws = (__bf16*)WS;                                        // [slot][128][64]
    float2* ml_ws = (float2*)((char*)WS + (size_t)NBH * 48 * 16384);   // [slot][128]

    const int dgi = t & 15;   // V staging: dims 4dgi..+3
    const int kgi = t >> 4;   // V staging: keys 4kgi..+3
    float4 kreg[4], vreg[4];

    const int ns = SEG_N[b24];

    // prefetch first tile of first segment
    {
        const int it0 = SEG_IT[b24][0];
        const int ktA0 = (2 * it0 - 16 > 0) ? (2 * it0 - 16) : 0;
        const int kt = ktA0 + SEG_J0[b24][0];
        #pragma unroll
        for (int i = 0; i < 4; ++i) kreg[i] = kp4[kt * 1024 + i * NT + t];
        #pragma unroll
        for (int kk = 0; kk < 4; ++kk) vreg[kk] = vp4[kt * 1024 + (4 * kgi + kk) * 16 + dgi];
    }

    for (int s = 0; s < ns; ++s) {
        const int item = SEG_IT[b24][s];
        const int j0   = SEG_J0[b24][s];
        const int j1   = SEG_J1[b24][s];
        const int sidx = SEG_SX[b24][s];
        const int ktA  = (2 * item - 16 > 0) ? (2 * item - 16) : 0;
        const int qw0  = item * 128 + 32 * w;   // this wave's first q (global)
        const int qi   = qw0 + c;

        // ---- Q B-fragments (pre-scaled) ----
        bf16x8 bq[4];
        {
            const float4* qp4 = (const float4*)(Q + basebh + (size_t)qi * 64);
            #pragma unroll
            for (int ks = 0; ks < 4; ++ks) {
                float4 f0 = qp4[4 * ks + 2 * hl];
                float4 f1 = qp4[4 * ks + 2 * hl + 1];
                bq[ks][0] = (__bf16)(f0.x * scale); bq[ks][1] = (__bf16)(f0.y * scale);
                bq[ks][2] = (__bf16)(f0.z * scale); bq[ks][3] = (__bf16)(f0.w * scale);
                bq[ks][4] = (__bf16)(f1.x * scale); bq[ks][5] = (__bf16)(f1.y * scale);
                bq[ks][6] = (__bf16)(f1.z * scale); bq[ks][7] = (__bf16)(f1.w * scale);
            }
        }

        // sink only in segment 0 of each item
        float mrun = (sidx == 0) ? sw : NEG_BIG;
        float lrun = (sidx == 0) ? 1.0f : 0.0f;
        f32x16 accO0, accO1;
        #pragma unroll
        for (int i = 0; i < 16; ++i) { accO0[i] = 0.0f; accO1[i] = 0.0f; }

        for (int j = j0; j < j1; ++j) {
            const int k0 = (ktA + j) * 64;
            __syncthreads();   // B1: prev tile's LDS reads done

            // ---- stage K [key][dim] ----
            #pragma unroll
            for (int i = 0; i < 4; ++i) {
                const int flat = i * NT + t;
                const int key = flat >> 4, dd = flat & 15;
                float4 f = kreg[i];
                bf16x4 b = { (__bf16)f.x, (__bf16)f.y, (__bf16)f.z, (__bf16)f.w };
                *(bf16x4*)&k_lds[key * SK + 4 * dd] = b;
            }
            // ---- stage V^T [dim][key] (register 4x4 transpose) ----
            {
                float4 a0 = vreg[0], a1 = vreg[1], a2 = vreg[2], a3 = vreg[3];
                bf16x4 w0 = { (__bf16)a0.x, (__bf16)a1.x, (__bf16)a2.x, (__bf16)a3.x };
                bf16x4 w1 = { (__bf16)a0.y, (__bf16)a1.y, (__bf16)a2.y, (__bf16)a3.y };
                bf16x4 w2 = { (__bf16)a0.z, (__bf16)a1.z, (__bf16)a2.z, (__bf16)a3.z };
                bf16x4 w3 = { (__bf16)a0.w, (__bf16)a1.w, (__bf16)a2.w, (__bf16)a3.w };
                *(bf16x4*)&v_lds[(4 * dgi + 0) * SV + 4 * kgi] = w0;
                *(bf16x4*)&v_lds[(4 * dgi + 1) * SV + 4 * kgi] = w1;
                *(bf16x4*)&v_lds[(4 * dgi + 2) * SV + 4 * kgi] = w2;
                *(bf16x4*)&v_lds[(4 * dgi + 3) * SV + 4 * kgi] = w3;
            }
            // ---- prefetch next tile (this seg, next seg, or none) ----
            int nkt = -1;
            if (j + 1 < j1) nkt = ktA + j + 1;
            else if (s + 1 < ns) {
                const int it2 = SEG_IT[b24][s + 1];
                const int ktA2 = (2 * it2 - 16 > 0) ? (2 * it2 - 16) : 0;
                nkt = ktA2 + SEG_J0[b24][s + 1];
            }
            if (nkt >= 0) {
                #pragma unroll
                for (int i = 0; i < 4; ++i) kreg[i] = kp4[nkt * 1024 + i * NT + t];
                #pragma unroll
                for (int kk = 0; kk < 4; ++kk) vreg[kk] = vp4[nkt * 1024 + (4 * kgi + kk) * 16 + dgi];
            }
            __syncthreads();   // B2: tiles visible

            // ---- S^T = K · Q^T ----
            f32x16 accS0, accS1;
            #pragma unroll
            for (int i = 0; i < 16; ++i) { accS0[i] = 0.0f; accS1[i] = 0.0f; }
            #pragma unroll
            for (int ks = 0; ks < 4; ++ks) {
                bf16x8 ka0 = *(const bf16x8*)&k_lds[c * SK + 16 * ks + 8 * hl];
                bf16x8 ka1 = *(const bf16x8*)&k_lds[(32 + c) * SK + 16 * ks + 8 * hl];
                accS0 = __builtin_amdgcn_mfma_f32_32x32x16_bf16(ka0, bq[ks], accS0, 0, 0, 0);
                accS1 = __builtin_amdgcn_mfma_f32_32x32x16_bf16(ka1, bq[ks], accS1, 0, 0, 0);
            }

            // ---- mask (wave-uniform skip when interior) ----
            const bool interior = (k0 + 63 <= qw0) && (qw0 + 31 - k0 <= W);
            if (!interior) {
                #pragma unroll
                for (int rg = 0; rg < 16; ++rg) {
                    const int kb  = (rg & 3) + 8 * (rg >> 2) + 4 * hl;
                    const int ki0 = k0 + kb, ki1 = k0 + 32 + kb;
                    if (!((ki0 <= qi) && (qi - ki0 <= W))) accS0[rg] = -1e30f;
                    if (!((ki1 <= qi) && (qi - ki1 <= W))) accS1[rg] = -1e30f;
                }
            }

            // ---- online softmax (per-lane 32 regs + one shfl pair) ----
            float mx = accS0[0];
            #pragma unroll
            for (int i = 1; i < 16; ++i) mx = fmaxf(mx, accS0[i]);
            #pragma unroll
            for (int i = 0; i < 16; ++i) mx = fmaxf(mx, accS1[i]);
            mx = fmaxf(mx, __shfl_xor(mx, 32, 64));
            const float mnew  = fmaxf(mrun, mx);
            const float alpha = __expf(mrun - mnew);
            float ps = 0.0f;
            #pragma unroll
            for (int i = 0; i < 16; ++i) { float p = __expf(accS0[i] - mnew); accS0[i] = p; ps += p; }
            #pragma unroll
            for (int i = 0; i < 16; ++i) { float p = __expf(accS1[i] - mnew); accS1[i] = p; ps += p; }
            ps += __shfl_xor(ps, 32, 64);
            lrun = lrun * alpha + ps;
            mrun = mnew;
            #pragma unroll
            for (int i = 0; i < 16; ++i) { accO0[i] *= alpha; accO1[i] *= alpha; }

            // ---- P -> per-wave LDS [q][key] (intra-wave, no barrier) ----
            __bf16* pw = p_lds + w * 32 * SPP;
            #pragma unroll
            for (int rg = 0; rg < 4; ++rg) {
                bf16x4 b0 = { (__bf16)accS0[4*rg+0], (__bf16)accS0[4*rg+1],
                              (__bf16)accS0[4*rg+2], (__bf16)accS0[4*rg+3] };
                bf16x4 b1 = { (__bf16)accS1[4*rg+0], (__bf16)accS1[4*rg+1],
                              (__bf16)accS1[4*rg+2], (__bf16)accS1[4*rg+3] };
                *(bf16x4*)&pw[c * SPP +      8 * rg + 4 * hl] = b0;
                *(bf16x4*)&pw[c * SPP + 32 + 8 * rg + 4 * hl] = b1;
            }

            // ---- O^T += V^T · P^T ----
            #pragma unroll
            for (int ks = 0; ks < 4; ++ks) {
                bf16x8 bp  = *(const bf16x8*)&pw[c * SPP + 16 * ks + 8 * hl];
                bf16x8 va0 = *(const bf16x8*)&v_lds[c * SV + 16 * ks + 8 * hl];
                bf16x8 va1 = *(const bf16x8*)&v_lds[(32 + c) * SV + 16 * ks + 8 * hl];
                accO0 = __builtin_amdgcn_mfma_f32_32x32x16_bf16(va0, bp, accO0, 0, 0, 0);
                accO1 = __builtin_amdgcn_mfma_f32_32x32x16_bf16(va1, bp, accO1, 0, 0, 0);
            }
        }

        // ---- write partials for this segment ----
        const int slot = (bh * 16 + item) * 3 + sidx;
        const int qrel = 32 * w + c;
        if (hl == 0) ml_ws[(size_t)slot * 128 + qrel] = make_float2(mrun, lrun);
        __bf16* Os = O_ws + (size_t)slot * 8192 + (size_t)qrel * 64;
        #pragma unroll
        for (int qd = 0; qd < 4; ++qd) {
            const int d0 = 8 * qd + 4 * hl;
            bf16x4 b0 = { (__bf16)accO0[4*qd+0], (__bf16)accO0[4*qd+1],
                          (__bf16)accO0[4*qd+2], (__bf16)accO0[4*qd+3] };
            bf16x4 b1 = { (__bf16)accO1[4*qd+0], (__bf16)accO1[4*qd+1],
                          (__bf16)accO1[4*qd+2], (__bf16)accO1[4*qd+3] };
            *(bf16x4*)&Os[d0]      = b0;
            *(bf16x4*)&Os[32 + d0] = b1;
        }
    }
}

__global__ __launch_bounds__(256) void flex_r5_combine(
    const void* __restrict__ WS, float* __restrict__ OUT, const int H, const int S)
{
    const int NBH  = gridDim.x / 16;
    const int bi   = blockIdx.x;
    const int bh   = bi >> 4;
    const int item = bi & 15;
    const int ns   = NSEG_ITEM[item];
    const int t    = threadIdx.x;
    const int q    = t >> 1;
    const int half = t & 1;

    const __bf16* O_ws = (const __bf16*)WS;
    const float2* ml_ws = (const float2*)((const char*)WS + (size_t)NBH * 48 * 16384);
    const int base = bi * 3;

    float m[3], lv[3], a[3];
    float mst = NEG_BIG;
    for (int s = 0; s < ns; ++s) {
        float2 e = ml_ws[(size_t)(base + s) * 128 + q];
        m[s] = e.x; lv[s] = e.y;
        mst = fmaxf(mst, m[s]);
    }
    float lst = 0.0f;
    for (int s = 0; s < ns; ++s) { a[s] = __expf(m[s] - mst); lst += a[s] * lv[s]; }
    const float inv = 1.0f / lst;

    float acc[32];
    #pragma unroll
    for (int i = 0; i < 32; ++i) acc[i] = 0.0f;
    for (int s = 0; s < ns; ++s) {
        const __bf16* Os = O_ws + (size_t)(base + s) * 8192 + (size_t)q * 64 + 32 * half;
        const float as = a[s];
        #pragma unroll
        for (int v8 = 0; v8 < 4; ++v8) {
            bf16x8 o = *(const bf16x8*)&Os[8 * v8];
            #pragma unroll
            for (int j = 0; j < 8; ++j) acc[8 * v8 + j] += as * (float)o[j];
        }
    }

    float* dst = OUT + (size_t)bh * S * 64 + (size_t)(item * 128 + q) * 64 + 32 * half;
    #pragma unroll
    for (int v4 = 0; v4 < 8; ++v4) {
        float4 f = { acc[4*v4+0] * inv, acc[4*v4+1] * inv,
                     acc[4*v4+2] * inv, acc[4*v4+3] * inv };
        *(float4*)&dst[4 * v4] = f;
    }
}

extern "C" void kernel_launch(void* const* d_in, const int* in_sizes, int n_in,
                              void* d_out, int out_size, void* d_ws, size_t ws_size,
                              hipStream_t stream) {
    const float* q     = (const float*)d_in[0];
    const float* k     = (const float*)d_in[1];
    const float* v     = (const float*)d_in[2];
    const float* sinkw = (const float*)d_in[3];
    const int*   swin  = (const int*)d_in[4];
    float* out = (float*)d_out;

    const int H = in_sizes[3];                   // 16
    const int S = 2048;
    const int B = in_sizes[0] / (H * S * 64);    // 2
    const int NBH = B * H;                       // 32

    // workspace: NBH*48 partial slots: O bf16 [128][64] + (m,l) f32 [128]
    // = NBH*48*(16384 + 1024) bytes = 26.7 MB for NBH=32.

    flex_r5_main<<<dim3(NBH * 24), NT, 0, stream>>>(q, k, v, sinkw, swin, d_ws, H, S);
    flex_r5_combine<<<dim3(NBH * 16), 256, 0, stream>>>(d_ws, out, H, S);
}